// Round 1
// baseline (353.151 us; speedup 1.0000x reference)
//
#include <hip/hip_runtime.h>
#include <hip/hip_bf16.h>
#include <math.h>

// Problem dims
#define NB 32
#define NS 512
#define NM 8
#define NH 512
#define NK 2048
#define WSTRIDE 2560   // W1 row stride (DIM1+DIM2)
#define FEPS 1e-5f

typedef __attribute__((ext_vector_type(4))) float f32x4;
typedef __attribute__((ext_vector_type(8))) short bf16x8;
typedef __attribute__((ext_vector_type(8))) unsigned short ushort8;

__device__ __forceinline__ unsigned short f2b(float f) {
  union { __hip_bfloat16 h; unsigned short u; } cv;
  cv.h = __float2bfloat16(f);
  return cv.u;
}

// ---------------------------------------------------------------------------
// Kernel 1: part_base[b*S+s][h] = sum_d base[b,s,d] * W1[h,d]   (bf16 MFMA)
// base = concat(face, fc, img, label_broadcast) along d (each 512 wide).
// A: [16384 x 2048] virtual, B^T: W1[:, :2048] = [512 x 2048] (K-contig).
// Tile 128x128, BK=32, 4 waves (2x2), 16x16x32 MFMA, double-buffered LDS.
// ---------------------------------------------------------------------------
#define LDSK 40   // LDS row stride in shorts: 32 data + 8 pad (bank spread)

__global__ __launch_bounds__(256, 2)
void gemm_base_kernel(const float* __restrict__ face,
                      const float* __restrict__ fcf,
                      const float* __restrict__ imgf,
                      const float* __restrict__ labf,
                      const float* __restrict__ W1,
                      float* __restrict__ pb)
{
  __shared__ unsigned short As[2][128 * LDSK];
  __shared__ unsigned short Bs[2][128 * LDSK];

  const int tid  = threadIdx.x;
  const int lane = tid & 63;
  const int wid  = tid >> 6;
  const int wr   = wid >> 1;          // wave row (0..1)
  const int wc   = wid & 1;           // wave col (0..1)
  const int blkm = blockIdx.x >> 2;   // 128 row tiles
  const int blkn = blockIdx.x & 3;    // 4 col tiles

  const int r  = tid >> 1;            // staging row 0..127
  const int ch = (tid & 1) << 4;      // staging col offset: 0 or 16 floats

  const int gr = blkm * 128 + r;      // global A row = b*512+s
  const int bb = gr >> 9;             // batch (tile never crosses batch)
  const int gh = blkn * 128 + r;      // global W1 row = h

  const int rl = lane & 15;
  const int kq = (lane >> 4) << 3;    // k-offset (shorts) for MFMA frag

  f32x4 acc[4][4];
  #pragma unroll
  for (int i = 0; i < 4; ++i)
    #pragma unroll
    for (int j = 0; j < 4; ++j)
      acc[i][j] = (f32x4){0.f, 0.f, 0.f, 0.f};

  float ra[16], rb[16];

#define LOAD_REGS(KT) do {                                                  \
    const int kt_ = (KT);                                                   \
    const int off_ = ((kt_ & 15) << 5) | ch;                                \
    const int reg_ = kt_ >> 4;                                              \
    const float* pa_;                                                       \
    if      (reg_ == 0) pa_ = face + (size_t)gr * 512 + off_;               \
    else if (reg_ == 1) pa_ = fcf  + (size_t)gr * 512 + off_;               \
    else if (reg_ == 2) pa_ = imgf + (size_t)gr * 512 + off_;               \
    else                pa_ = labf + (size_t)bb * 512 + off_;               \
    const float* pw_ = W1 + (size_t)gh * WSTRIDE + (kt_ << 5) + ch;         \
    _Pragma("unroll")                                                       \
    for (int i_ = 0; i_ < 4; ++i_) {                                        \
      f32x4 va_ = *(const f32x4*)(pa_ + 4 * i_);                            \
      f32x4 vb_ = *(const f32x4*)(pw_ + 4 * i_);                            \
      ra[4*i_+0] = va_[0]; ra[4*i_+1] = va_[1];                             \
      ra[4*i_+2] = va_[2]; ra[4*i_+3] = va_[3];                             \
      rb[4*i_+0] = vb_[0]; rb[4*i_+1] = vb_[1];                             \
      rb[4*i_+2] = vb_[2]; rb[4*i_+3] = vb_[3];                             \
    }                                                                       \
  } while (0)

#define WRITE_LDS(BUF) do {                                                 \
    ushort8 a0_, a1_, b0_, b1_;                                             \
    _Pragma("unroll")                                                       \
    for (int j_ = 0; j_ < 8; ++j_) {                                        \
      a0_[j_] = f2b(ra[j_]);   a1_[j_] = f2b(ra[8 + j_]);                   \
      b0_[j_] = f2b(rb[j_]);   b1_[j_] = f2b(rb[8 + j_]);                   \
    }                                                                       \
    *(ushort8*)&As[BUF][r * LDSK + ch]     = a0_;                           \
    *(ushort8*)&As[BUF][r * LDSK + ch + 8] = a1_;                           \
    *(ushort8*)&Bs[BUF][r * LDSK + ch]     = b0_;                           \
    *(ushort8*)&Bs[BUF][r * LDSK + ch + 8] = b1_;                           \
  } while (0)

#define COMPUTE(BUF) do {                                                   \
    bf16x8 af_[4], bf_[4];                                                  \
    _Pragma("unroll")                                                       \
    for (int m_ = 0; m_ < 4; ++m_)                                          \
      af_[m_] = *(const bf16x8*)&As[BUF][(wr*64 + m_*16 + rl) * LDSK + kq]; \
    _Pragma("unroll")                                                       \
    for (int n_ = 0; n_ < 4; ++n_)                                          \
      bf_[n_] = *(const bf16x8*)&Bs[BUF][(wc*64 + n_*16 + rl) * LDSK + kq]; \
    _Pragma("unroll")                                                       \
    for (int m_ = 0; m_ < 4; ++m_)                                          \
      _Pragma("unroll")                                                     \
      for (int n_ = 0; n_ < 4; ++n_)                                        \
        acc[m_][n_] = __builtin_amdgcn_mfma_f32_16x16x32_bf16(              \
            af_[m_], bf_[n_], acc[m_][n_], 0, 0, 0);                        \
  } while (0)

  LOAD_REGS(0);
  WRITE_LDS(0);
  __syncthreads();

  int buf = 0;
  for (int kt = 0; kt < 64; ++kt) {
    if (kt < 63) LOAD_REGS(kt + 1);   // issue next-tile global loads early
    COMPUTE(buf);
    if (kt < 63) WRITE_LDS(buf ^ 1);  // convert + stage into other buffer
    __syncthreads();                  // single barrier per K-step
    buf ^= 1;
  }

  // Epilogue: C/D layout col=lane&15, row=(lane>>4)*4+reg  (m89-verified)
  const int crow = blkm * 128 + wr * 64;
  const int ccol = blkn * 128 + wc * 64 + rl;
  #pragma unroll
  for (int m = 0; m < 4; ++m)
    #pragma unroll
    for (int n = 0; n < 4; ++n)
      #pragma unroll
      for (int j = 0; j < 4; ++j) {
        const int row = crow + m * 16 + (lane >> 4) * 4 + j;
        pb[(size_t)row * 512 + ccol + n * 16] = acc[m][n][j];
      }

#undef LOAD_REGS
#undef WRITE_LDS
#undef COMPUTE
}

// ---------------------------------------------------------------------------
// Kernel 2: part_mem[b][m][h] = sum_d memory[b,m,d]*W1[h,2048+d] + b1[h]
// fp32 exact. One block per batch; W1b read once per block (L2/L3 resident).
// ---------------------------------------------------------------------------
__global__ __launch_bounds__(256)
void pm_kernel(const float* __restrict__ memory,
               const float* __restrict__ W1,
               const float* __restrict__ b1,
               float* __restrict__ pm)
{
  __shared__ float ms[NM * 512];
  const int b = blockIdx.x;
  const int t = threadIdx.x;

  const float* src = memory + (size_t)b * NM * 512;
  #pragma unroll
  for (int i = 0; i < 4; ++i)
    ((f32x4*)ms)[t + i * 256] = ((const f32x4*)src)[t + i * 256];
  __syncthreads();

  #pragma unroll
  for (int hh = 0; hh < 2; ++hh) {
    const int h = t + hh * 256;
    const float* wrow = W1 + (size_t)h * WSTRIDE + 2048;
    float acc[NM];
    #pragma unroll
    for (int m = 0; m < NM; ++m) acc[m] = 0.f;
    for (int d = 0; d < 512; d += 4) {
      f32x4 w = *(const f32x4*)(wrow + d);
      #pragma unroll
      for (int m = 0; m < NM; ++m) {
        f32x4 mv = *(const f32x4*)&ms[m * 512 + d];
        acc[m] += w[0]*mv[0] + w[1]*mv[1] + w[2]*mv[2] + w[3]*mv[3];
      }
    }
    const float bias = b1[h];
    #pragma unroll
    for (int m = 0; m < NM; ++m)
      pm[((size_t)b * NM + m) * 512 + h] = acc[m] + bias;
  }
}

// ---------------------------------------------------------------------------
// Kernel 3a: e[b][m*512+s] = sum_h tanh(pb[b,s,h]+pm[b,m,h]) * w2[h]
// Never materializes h[B,M,S,H]. Block = (b, 16-s tile), 128 threads
// (thread = 16 s_local x 8 m). Rows padded to 516 f32 -> conflict-free.
// ---------------------------------------------------------------------------
__global__ __launch_bounds__(128)
void e_kernel(const float* __restrict__ pb,
              const float* __restrict__ pm,
              const float* __restrict__ w2,
              float* __restrict__ e)
{
  __shared__ float pbs[16 * 516];
  __shared__ float pms[NM * 516];
  __shared__ float w2s[512];

  const int b  = blockIdx.x;   // 0..31
  const int st = blockIdx.y;   // 0..31
  const int t  = threadIdx.x;  // 0..127

  const float* pbsrc = pb + ((size_t)b * NS + st * 16) * 512;
  #pragma unroll
  for (int i = 0; i < 16; ++i) {
    const int fi = t + i * 128;           // float4 index into 16x512
    f32x4 v = ((const f32x4*)pbsrc)[fi];
    const int f32i = fi * 4;
    *(f32x4*)&pbs[(f32i >> 9) * 516 + (f32i & 511)] = v;
  }
  const float* pmsrc = pm + (size_t)b * NM * 512;
  #pragma unroll
  for (int i = 0; i < 8; ++i) {
    const int fi = t + i * 128;
    f32x4 v = ((const f32x4*)pmsrc)[fi];
    const int f32i = fi * 4;
    *(f32x4*)&pms[(f32i >> 9) * 516 + (f32i & 511)] = v;
  }
  ((f32x4*)w2s)[t] = ((const f32x4*)w2)[t];
  __syncthreads();

  const int sl = t >> 3;
  const int m  = t & 7;
  const float* prow = &pbs[sl * 516];
  const float* mrow = &pms[m * 516];

  float acc = 0.f;
  for (int h = 0; h < 512; h += 4) {
    f32x4 pv = *(const f32x4*)&prow[h];
    f32x4 mv = *(const f32x4*)&mrow[h];
    f32x4 wv = *(const f32x4*)&w2s[h];
    #pragma unroll
    for (int j = 0; j < 4; ++j) {
      const float x  = pv[j] + mv[j];
      const float ex = __expf(x + x);                  // exp(2x)
      const float th = 1.f - __fdividef(2.f, ex + 1.f); // tanh(x)
      acc += wv[j] * th;
    }
  }
  e[(size_t)b * (NM * NS) + m * NS + st * 16 + sl] = acc;
}

// ---------------------------------------------------------------------------
// Kernel 4: per-batch softmax over 4096, mask (j mod 512), renorm, alpha out,
// context[b][d] = sum_s (sum_m alpha[m][s]) * face[b,s,d]
// alpha3 = p*mask / (sA*(sM/sA + EPS))  ==  reference exactly.
// ---------------------------------------------------------------------------
__global__ __launch_bounds__(256)
void softmax_ctx_kernel(const float* __restrict__ e,
                        const float* __restrict__ face,
                        const float* __restrict__ face_mask,
                        float* __restrict__ out_alpha,
                        float* __restrict__ out_ctx)
{
  __shared__ float ev[NM * NS];
  __shared__ float msk[NS];
  __shared__ float ws[NS];
  __shared__ float redX[4], redA[4], redM[4];

  const int b = blockIdx.x;
  const int t = threadIdx.x;
  const int lane = t & 63;
  const int wv = t >> 6;

  const float* erow = e + (size_t)b * (NM * NS);
  #pragma unroll
  for (int i = 0; i < 4; ++i)
    ((f32x4*)ev)[t + i * 256] = ((const f32x4*)erow)[t + i * 256];
  if (t < 128)
    ((f32x4*)msk)[t] = ((const f32x4*)(face_mask + (size_t)b * NS))[t];
  __syncthreads();

  // block max
  float mx = -3.402823466e38f;
  for (int i = t; i < NM * NS; i += 256) mx = fmaxf(mx, ev[i]);
  #pragma unroll
  for (int o = 32; o >= 1; o >>= 1) mx = fmaxf(mx, __shfl_xor(mx, o));
  if (lane == 0) redX[wv] = mx;
  __syncthreads();
  mx = fmaxf(fmaxf(redX[0], redX[1]), fmaxf(redX[2], redX[3]));

  // exp, full sum, masked sum
  float sA = 0.f, sM = 0.f;
  for (int i = t; i < NM * NS; i += 256) {
    const float p = __expf(ev[i] - mx);
    ev[i] = p;
    sA += p;
    sM += p * msk[i & 511];
  }
  #pragma unroll
  for (int o = 32; o >= 1; o >>= 1) {
    sA += __shfl_xor(sA, o);
    sM += __shfl_xor(sM, o);
  }
  if (lane == 0) { redA[wv] = sA; redM[wv] = sM; }
  __syncthreads();
  sA = redA[0] + redA[1] + redA[2] + redA[3];
  sM = redM[0] + redM[1] + redM[2] + redM[3];

  const float rr = sM / sA;
  const float scale = 1.f / (sA * (rr + FEPS));

  for (int i = t; i < NM * NS; i += 256) {
    const float a = ev[i] * msk[i & 511] * scale;
    ev[i] = a;
    out_alpha[(size_t)b * (NM * NS) + i] = a;
  }
  __syncthreads();

  // ws[s] = sum_m alpha[m][s]
  for (int s = t; s < NS; s += 256) {
    float w = 0.f;
    #pragma unroll
    for (int m = 0; m < NM; ++m) w += ev[m * NS + s];
    ws[s] = w;
  }
  __syncthreads();

  const float* fb = face + (size_t)b * NS * 512;
  for (int d = t; d < 512; d += 256) {
    float c = 0.f;
    for (int s = 0; s < NS; ++s) c += ws[s] * fb[(size_t)s * 512 + d];
    out_ctx[(size_t)b * 512 + d] = c;
  }
}

// ---------------------------------------------------------------------------
extern "C" void kernel_launch(void* const* d_in, const int* in_sizes, int n_in,
                              void* d_out, int out_size, void* d_ws, size_t ws_size,
                              hipStream_t stream)
{
  const float* fc_feat  = (const float*)d_in[0];
  const float* img_feat = (const float*)d_in[1];
  const float* label    = (const float*)d_in[2];
  const float* memory   = (const float*)d_in[3];
  const float* face     = (const float*)d_in[4];
  const float* fmask    = (const float*)d_in[5];
  const float* W1       = (const float*)d_in[6];
  const float* b1       = (const float*)d_in[7];
  const float* w2       = (const float*)d_in[8];

  float* out       = (float*)d_out;
  float* alpha_out = out;                      // [32, 4096]
  float* ctx_out   = out + (size_t)NB * NM * NS; // [32, 512]

  char* ws = (char*)d_ws;
  float* pb = (float*)ws;                                   // 16384*512 f32 = 33.5 MB
  float* pm = (float*)(ws + (size_t)NB * NS * 512 * 4);     // 32*8*512 f32
  float* ee = (float*)(ws + (size_t)NB * NS * 512 * 4
                          + (size_t)NB * NM * 512 * 4);     // 32*4096 f32

  // concat order in reference: [face, fc, img, label]
  gemm_base_kernel<<<512, 256, 0, stream>>>(face, fc_feat, img_feat, label, W1, pb);
  pm_kernel<<<NB, 256, 0, stream>>>(memory, W1, b1, pm);
  e_kernel<<<dim3(NB, NS / 16), 128, 0, stream>>>(pb, pm, w2, ee);
  softmax_ctx_kernel<<<NB, 256, 0, stream>>>(ee, face, fmask, alpha_out, ctx_out);
}

// Round 4
// 330.704 us; speedup vs baseline: 1.0679x; 1.0679x over previous
//
#include <hip/hip_runtime.h>
#include <hip/hip_bf16.h>
#include <math.h>

// Problem dims
#define NB 32
#define NS 512
#define NM 8
#define NH 512
#define WSTRIDE 2560   // W1 row stride (DIM1+DIM2)
#define FEPS 1e-5f

typedef __attribute__((ext_vector_type(4))) float f32x4;
typedef __attribute__((ext_vector_type(8))) short bf16x8;
typedef __attribute__((ext_vector_type(8))) unsigned short ushort8;

__device__ __forceinline__ unsigned short f2b(float f) {
  union { __hip_bfloat16 h; unsigned short u; } cv;
  cv.h = __float2bfloat16(f);
  return cv.u;
}

// ---------------------------------------------------------------------------
// Kernel 1: part_base[b*S+s][h] = sum_d base[b,s,d] * W1[h,d]   (bf16 MFMA)
// Split-K x2 (KSTEPS=32 each half) -> 1024 blocks -> 4 blocks/CU.
// Tile 128x128, BK=32, 4 waves (2x2), 16x16x32 MFMA, double-buffered LDS.
// XCD-contiguous bijective block swizzle (grid % 8 == 0).
// ---------------------------------------------------------------------------
#define LDSK 40   // LDS row stride in shorts: 32 data + 8 pad

template<int KSTEPS>
__global__ __launch_bounds__(256, 4)
void gemm_base_kernel(const float* __restrict__ face,
                      const float* __restrict__ fcf,
                      const float* __restrict__ imgf,
                      const float* __restrict__ labf,
                      const float* __restrict__ W1,
                      float* __restrict__ pb)
{
  __shared__ unsigned short As[2][128 * LDSK];
  __shared__ unsigned short Bs[2][128 * LDSK];

  const int tid  = threadIdx.x;
  const int lane = tid & 63;
  const int wid  = tid >> 6;
  const int wr   = wid >> 1;
  const int wc   = wid & 1;

  // XCD swizzle: contiguous sid chunk per XCD (bijective: grid % 8 == 0)
  const int bid = blockIdx.x;
  const int cpx = gridDim.x >> 3;
  const int sid = (bid & 7) * cpx + (bid >> 3);
  const int kk   = sid >> 9;          // K-half (0 for non-split grid=512)
  const int blkm = (sid >> 2) & 127;  // 128 row tiles
  const int blkn = sid & 3;           // 4 col tiles

  const int r  = tid >> 1;            // staging row 0..127
  const int ch = (tid & 1) << 4;      // staging col offset: 0 or 16 floats

  const int gr = blkm * 128 + r;      // global A row = b*512+s
  const int bb = gr >> 9;             // batch
  const int gh = blkn * 128 + r;      // global W1 row = h

  const int rl = lane & 15;
  const int kq = (lane >> 4) << 3;    // k-offset (shorts) for MFMA frag

  f32x4 acc[4][4];
  #pragma unroll
  for (int i = 0; i < 4; ++i)
    #pragma unroll
    for (int j = 0; j < 4; ++j)
      acc[i][j] = (f32x4){0.f, 0.f, 0.f, 0.f};

  float ra[16], rb[16];

#define LOAD_REGS(KTG) do {                                                 \
    const int kt_ = (KTG);                                                  \
    const int off_ = ((kt_ & 15) << 5) | ch;                                \
    const int reg_ = kt_ >> 4;                                              \
    const float* pa_;                                                       \
    if      (reg_ == 0) pa_ = face + (size_t)gr * 512 + off_;               \
    else if (reg_ == 1) pa_ = fcf  + (size_t)gr * 512 + off_;               \
    else if (reg_ == 2) pa_ = imgf + (size_t)gr * 512 + off_;               \
    else                pa_ = labf + (size_t)bb * 512 + off_;               \
    const float* pw_ = W1 + (size_t)gh * WSTRIDE + (kt_ << 5) + ch;         \
    _Pragma("unroll")                                                       \
    for (int i_ = 0; i_ < 4; ++i_) {                                        \
      f32x4 va_ = *(const f32x4*)(pa_ + 4 * i_);                            \
      f32x4 vb_ = *(const f32x4*)(pw_ + 4 * i_);                            \
      ra[4*i_+0] = va_[0]; ra[4*i_+1] = va_[1];                             \
      ra[4*i_+2] = va_[2]; ra[4*i_+3] = va_[3];                             \
      rb[4*i_+0] = vb_[0]; rb[4*i_+1] = vb_[1];                             \
      rb[4*i_+2] = vb_[2]; rb[4*i_+3] = vb_[3];                             \
    }                                                                       \
  } while (0)

#define WRITE_LDS(BUF) do {                                                 \
    ushort8 a0_, a1_, b0_, b1_;                                             \
    _Pragma("unroll")                                                       \
    for (int j_ = 0; j_ < 8; ++j_) {                                        \
      a0_[j_] = f2b(ra[j_]);   a1_[j_] = f2b(ra[8 + j_]);                   \
      b0_[j_] = f2b(rb[j_]);   b1_[j_] = f2b(rb[8 + j_]);                   \
    }                                                                       \
    *(ushort8*)&As[BUF][r * LDSK + ch]     = a0_;                           \
    *(ushort8*)&As[BUF][r * LDSK + ch + 8] = a1_;                           \
    *(ushort8*)&Bs[BUF][r * LDSK + ch]     = b0_;                           \
    *(ushort8*)&Bs[BUF][r * LDSK + ch + 8] = b1_;                           \
  } while (0)

#define COMPUTE(BUF) do {                                                   \
    bf16x8 af_[4], bf_[4];                                                  \
    _Pragma("unroll")                                                       \
    for (int m_ = 0; m_ < 4; ++m_)                                          \
      af_[m_] = *(const bf16x8*)&As[BUF][(wr*64 + m_*16 + rl) * LDSK + kq]; \
    _Pragma("unroll")                                                       \
    for (int n_ = 0; n_ < 4; ++n_)                                          \
      bf_[n_] = *(const bf16x8*)&Bs[BUF][(wc*64 + n_*16 + rl) * LDSK + kq]; \
    _Pragma("unroll")                                                       \
    for (int m_ = 0; m_ < 4; ++m_)                                          \
      _Pragma("unroll")                                                     \
      for (int n_ = 0; n_ < 4; ++n_)                                        \
        acc[m_][n_] = __builtin_amdgcn_mfma_f32_16x16x32_bf16(              \
            af_[m_], bf_[n_], acc[m_][n_], 0, 0, 0);                        \
  } while (0)

  const int kbase = kk * 32;          // 32 kt per K-half
  LOAD_REGS(kbase);
  WRITE_LDS(0);
  __syncthreads();

  int buf = 0;
  #pragma unroll 1
  for (int kt = 0; kt < KSTEPS; ++kt) {
    if (kt < KSTEPS - 1) LOAD_REGS(kbase + kt + 1);
    COMPUTE(buf);
    if (kt < KSTEPS - 1) WRITE_LDS(buf ^ 1);
    __syncthreads();
    buf ^= 1;
  }

  // C/D layout: col=lane&15, row=(lane>>4)*4+reg (m89-verified)
  float* pbo = pb + (size_t)kk * ((size_t)NB * NS * 512);
  const int crow = blkm * 128 + wr * 64;
  const int ccol = blkn * 128 + wc * 64 + rl;
  #pragma unroll
  for (int m = 0; m < 4; ++m)
    #pragma unroll
    for (int n = 0; n < 4; ++n)
      #pragma unroll
      for (int j = 0; j < 4; ++j) {
        const int row = crow + m * 16 + (lane >> 4) * 4 + j;
        pbo[(size_t)row * 512 + ccol + n * 16] = acc[m][n][j];
      }

#undef LOAD_REGS
#undef WRITE_LDS
#undef COMPUTE
}

// ---------------------------------------------------------------------------
// Kernel 2: part_mem[b][m][h] = sum_d memory[b,m,d]*W1[h,2048+d] + b1[h]
// fp32 exact. Grid (32 b, 8 h-tiles) = 256 blocks. Lanes-over-d coalesced
// W reads + butterfly reduce.
// W1b slice is 512 floats wide: chunks at d = l*4 (0..255) and 256+l*4.
// ---------------------------------------------------------------------------
__global__ __launch_bounds__(256)
void pm_kernel(const float* __restrict__ memory,
               const float* __restrict__ W1,
               const float* __restrict__ b1,
               float* __restrict__ pm)
{
  __shared__ float ms[NM * 512];
  const int b  = blockIdx.x;
  const int ht = blockIdx.y;
  const int t  = threadIdx.x;
  const int w  = t >> 6;
  const int l  = t & 63;

  const float* src = memory + (size_t)b * NM * 512;
  #pragma unroll
  for (int i = 0; i < 4; ++i)
    ((f32x4*)ms)[t + i * 256] = ((const f32x4*)src)[t + i * 256];
  __syncthreads();

  #pragma unroll 1
  for (int i = 0; i < 16; ++i) {
    const int h = ht * 64 + w * 16 + i;
    const float* wrow = W1 + (size_t)h * WSTRIDE + 2048;
    const f32x4 w0 = *(const f32x4*)(wrow + l * 4);        // d: 0..255
    const f32x4 w1 = *(const f32x4*)(wrow + 256 + l * 4);  // d: 256..511 (FIXED)
    float part[NM];
    #pragma unroll
    for (int m = 0; m < NM; ++m) {
      const f32x4 m0 = *(const f32x4*)&ms[m * 512 + l * 4];
      const f32x4 m1 = *(const f32x4*)&ms[m * 512 + 256 + l * 4];
      part[m] = w0[0]*m0[0] + w0[1]*m0[1] + w0[2]*m0[2] + w0[3]*m0[3]
              + w1[0]*m1[0] + w1[1]*m1[1] + w1[2]*m1[2] + w1[3]*m1[3];
    }
    #pragma unroll
    for (int off = 32; off >= 1; off >>= 1)
      #pragma unroll
      for (int m = 0; m < NM; ++m)
        part[m] += __shfl_xor(part[m], off);
    if (l == 0) {
      const float bias = b1[h];
      #pragma unroll
      for (int m = 0; m < NM; ++m)
        pm[((size_t)b * NM + m) * 512 + h] = part[m] + bias;
    }
  }
}

// ---------------------------------------------------------------------------
// Kernel 3: e[b][m*512+s] = sum_h tanh(pb[b,s,h]+pm[b,m,h]) * w2[h]
// SPLIT: pb = pb0 + pb1 (split-K partials summed at staging).
// ---------------------------------------------------------------------------
template<int SPLIT>
__global__ __launch_bounds__(128)
void e_kernel(const float* __restrict__ pb0,
              const float* __restrict__ pb1,
              const float* __restrict__ pm,
              const float* __restrict__ w2,
              float* __restrict__ e)
{
  __shared__ float pbs[16 * 516];
  __shared__ float pms[NM * 516];
  __shared__ float w2s[512];

  const int b  = blockIdx.x;
  const int st = blockIdx.y;
  const int t  = threadIdx.x;

  const f32x4* s0 = (const f32x4*)(pb0 + ((size_t)b * NS + st * 16) * 512);
  const f32x4* s1 = (const f32x4*)(pb1 + ((size_t)b * NS + st * 16) * 512);
  #pragma unroll
  for (int i = 0; i < 16; ++i) {
    const int fi = t + i * 128;
    f32x4 v = s0[fi];
    if (SPLIT) {
      f32x4 v1 = s1[fi];
      v[0]+=v1[0]; v[1]+=v1[1]; v[2]+=v1[2]; v[3]+=v1[3];
    }
    const int f32i = fi * 4;
    *(f32x4*)&pbs[(f32i >> 9) * 516 + (f32i & 511)] = v;
  }
  const float* pmsrc = pm + (size_t)b * NM * 512;
  #pragma unroll
  for (int i = 0; i < 8; ++i) {
    const int fi = t + i * 128;
    f32x4 v = ((const f32x4*)pmsrc)[fi];
    const int f32i = fi * 4;
    *(f32x4*)&pms[(f32i >> 9) * 516 + (f32i & 511)] = v;
  }
  ((f32x4*)w2s)[t] = ((const f32x4*)w2)[t];
  __syncthreads();

  const int sl = t >> 3;
  const int m  = t & 7;
  const float* prow = &pbs[sl * 516];
  const float* mrow = &pms[m * 516];

  float acc = 0.f;
  for (int h = 0; h < 512; h += 4) {
    f32x4 pv = *(const f32x4*)&prow[h];
    f32x4 mv = *(const f32x4*)&mrow[h];
    f32x4 wv = *(const f32x4*)&w2s[h];
    #pragma unroll
    for (int j = 0; j < 4; ++j) {
      const float x  = pv[j] + mv[j];
      const float ex = __expf(x + x);
      const float th = 1.f - __fdividef(2.f, ex + 1.f);
      acc += wv[j] * th;
    }
  }
  e[(size_t)b * (NM * NS) + m * NS + st * 16 + sl] = acc;
}

// ---------------------------------------------------------------------------
// Kernel 4: per-batch softmax over 4096, mask (j mod 512), renorm.
// Writes alpha and ws[s] = sum_m alpha[m][s] (for ctx kernel).
// ---------------------------------------------------------------------------
__global__ __launch_bounds__(256)
void softmax_kernel(const float* __restrict__ e,
                    const float* __restrict__ face_mask,
                    float* __restrict__ out_alpha,
                    float* __restrict__ wsum)
{
  __shared__ float ev[NM * NS];
  __shared__ float msk[NS];
  __shared__ float redX[4], redA[4], redM[4];

  const int b = blockIdx.x;
  const int t = threadIdx.x;
  const int lane = t & 63;
  const int wv = t >> 6;

  const float* erow = e + (size_t)b * (NM * NS);
  #pragma unroll
  for (int i = 0; i < 4; ++i)
    ((f32x4*)ev)[t + i * 256] = ((const f32x4*)erow)[t + i * 256];
  if (t < 128)
    ((f32x4*)msk)[t] = ((const f32x4*)(face_mask + (size_t)b * NS))[t];
  __syncthreads();

  float mx = -3.402823466e38f;
  for (int i = t; i < NM * NS; i += 256) mx = fmaxf(mx, ev[i]);
  #pragma unroll
  for (int o = 32; o >= 1; o >>= 1) mx = fmaxf(mx, __shfl_xor(mx, o));
  if (lane == 0) redX[wv] = mx;
  __syncthreads();
  mx = fmaxf(fmaxf(redX[0], redX[1]), fmaxf(redX[2], redX[3]));

  float sA = 0.f, sM = 0.f;
  for (int i = t; i < NM * NS; i += 256) {
    const float p = __expf(ev[i] - mx);
    ev[i] = p;
    sA += p;
    sM += p * msk[i & 511];
  }
  #pragma unroll
  for (int o = 32; o >= 1; o >>= 1) {
    sA += __shfl_xor(sA, o);
    sM += __shfl_xor(sM, o);
  }
  if (lane == 0) { redA[wv] = sA; redM[wv] = sM; }
  __syncthreads();
  sA = redA[0] + redA[1] + redA[2] + redA[3];
  sM = redM[0] + redM[1] + redM[2] + redM[3];

  const float rr = sM / sA;
  const float scale = 1.f / (sA * (rr + FEPS));

  for (int i = t; i < NM * NS; i += 256) {
    const float a = ev[i] * msk[i & 511] * scale;
    ev[i] = a;
    out_alpha[(size_t)b * (NM * NS) + i] = a;
  }
  __syncthreads();

  for (int s = t; s < NS; s += 256) {
    float w = 0.f;
    #pragma unroll
    for (int m = 0; m < NM; ++m) w += ev[m * NS + s];
    wsum[(size_t)b * NS + s] = w;
  }
}

// ---------------------------------------------------------------------------
// Kernel 5: context[b][d] = sum_s ws[s] * face[b,s,d]
// Grid (32, 8 s-chunks) = 256 blocks; f32x4 coalesced; atomicAdd partials.
// ---------------------------------------------------------------------------
__global__ __launch_bounds__(128)
void ctx_kernel(const float* __restrict__ wsum,
                const float* __restrict__ face,
                float* __restrict__ out_ctx)
{
  const int b  = blockIdx.x;
  const int sq = blockIdx.y;
  const int t  = threadIdx.x;   // 0..127 -> f32x4 over d

  f32x4 acc = (f32x4){0.f, 0.f, 0.f, 0.f};
  const int s0 = sq * 64;
  #pragma unroll 4
  for (int si = 0; si < 64; ++si) {
    const int s = s0 + si;
    const float w = wsum[(size_t)b * NS + s];
    const f32x4 fv = ((const f32x4*)(face + ((size_t)b * NS + s) * 512))[t];
    acc[0] += w * fv[0]; acc[1] += w * fv[1];
    acc[2] += w * fv[2]; acc[3] += w * fv[3];
  }
  float* dst = out_ctx + (size_t)b * 512 + t * 4;
  atomicAdd(dst + 0, acc[0]);
  atomicAdd(dst + 1, acc[1]);
  atomicAdd(dst + 2, acc[2]);
  atomicAdd(dst + 3, acc[3]);
}

// ---------------------------------------------------------------------------
extern "C" void kernel_launch(void* const* d_in, const int* in_sizes, int n_in,
                              void* d_out, int out_size, void* d_ws, size_t ws_size,
                              hipStream_t stream)
{
  const float* fc_feat  = (const float*)d_in[0];
  const float* img_feat = (const float*)d_in[1];
  const float* label    = (const float*)d_in[2];
  const float* memory   = (const float*)d_in[3];
  const float* face     = (const float*)d_in[4];
  const float* fmask    = (const float*)d_in[5];
  const float* W1       = (const float*)d_in[6];
  const float* b1       = (const float*)d_in[7];
  const float* w2       = (const float*)d_in[8];

  float* out       = (float*)d_out;
  float* alpha_out = out;                        // [32, 4096]
  float* ctx_out   = out + (size_t)NB * NM * NS; // [32, 512]

  const size_t szPB = (size_t)NB * NS * 512 * 4;   // 33.5 MB
  const size_t szPM = (size_t)NB * NM * 512 * 4;
  const size_t szE  = (size_t)NB * NM * NS * 4;
  const size_t need_split = 2 * szPB + szPM + szE + (size_t)NB * NS * 4;
  const bool split = ws_size >= need_split;

  char* ws = (char*)d_ws;
  float* pb0 = (float*)ws;
  float* pb1 = split ? (float*)(ws + szPB) : pb0;
  char*  tail = ws + (split ? 2 * szPB : szPB);
  float* pm = (float*)tail;
  float* ee = (float*)(tail + szPM);
  float* wsum = (float*)(tail + szPM + szE);

  hipMemsetAsync(ctx_out, 0, (size_t)NB * 512 * 4, stream);

  if (split)
    gemm_base_kernel<32><<<1024, 256, 0, stream>>>(face, fc_feat, img_feat, label, W1, pb0);
  else
    gemm_base_kernel<64><<<512, 256, 0, stream>>>(face, fc_feat, img_feat, label, W1, pb0);

  pm_kernel<<<dim3(NB, 8), 256, 0, stream>>>(memory, W1, b1, pm);

  if (split)
    e_kernel<1><<<dim3(NB, NS / 16), 128, 0, stream>>>(pb0, pb1, pm, w2, ee);
  else
    e_kernel<0><<<dim3(NB, NS / 16), 128, 0, stream>>>(pb0, pb1, pm, w2, ee);

  softmax_kernel<<<NB, 256, 0, stream>>>(ee, fmask, alpha_out, wsum);
  ctx_kernel<<<dim3(NB, 8), 128, 0, stream>>>(wsum, face, ctx_out);
}

// Round 6
// 296.977 us; speedup vs baseline: 1.1892x; 1.1136x over previous
//
#include <hip/hip_runtime.h>
#include <hip/hip_bf16.h>
#include <math.h>

// Problem dims
#define NB 32
#define NS 512
#define NM 8
#define NH 512
#define WSTRIDE 2560   // W1 row stride (DIM1+DIM2)
#define FEPS 1e-5f

typedef __attribute__((ext_vector_type(4))) float f32x4;
typedef __attribute__((ext_vector_type(8))) short bf16x8;
typedef __attribute__((ext_vector_type(8))) unsigned short ushort8;

__device__ __forceinline__ unsigned short f2b(float f) {
  union { __hip_bfloat16 h; unsigned short u; } cv;
  cv.h = __float2bfloat16(f);
  return cv.u;
}

// ---------------------------------------------------------------------------
// Kernel 1: part_base[b*S+s][h] = sum_d base[b,s,d] * W1[h,d]   (bf16 MFMA)
// Full-K, tile 128x64 (M x H) -> grid 128*8 = 1024 blocks.
// 4 waves (2x2), wave tile 64x32, acc[4][2], 16x16x32 MFMA.
// DEPTH-2 REGISTER PREFETCH: two named load sets; loads for tile kt+2 are
// issued while LDS-write consumes the set loaded 1.5 iterations earlier, so
// the vmcnt wait hits landed data (fixes the ~700cy/K-step latency stall
// measured in R4: VALU 8%, MFMA 11%, HBM 14% -> all idle).
// ---------------------------------------------------------------------------
#define LDSK 40   // LDS row stride in shorts: 32 data + 8 pad (2-way max)

__global__ __launch_bounds__(256, 3)
void gemm_base_kernel(const float* __restrict__ face,
                      const float* __restrict__ fcf,
                      const float* __restrict__ imgf,
                      const float* __restrict__ labf,
                      const float* __restrict__ W1,
                      float* __restrict__ pb)
{
  __shared__ unsigned short As[2][128 * LDSK];
  __shared__ unsigned short Bs[2][64 * LDSK];

  const int tid  = threadIdx.x;
  const int lane = tid & 63;
  const int wid  = tid >> 6;
  const int wr   = wid >> 1;           // wave row (0..1)
  const int wc   = wid & 1;            // wave col (0..1)

  // XCD swizzle: contiguous sid chunk per XCD (bijective: 1024 % 8 == 0)
  const int bid = blockIdx.x;
  const int cpx = gridDim.x >> 3;
  const int sid = (bid & 7) * cpx + (bid >> 3);
  const int blkm = sid >> 3;           // 0..127 (128-row tiles)
  const int blkn = sid & 7;            // 0..7   (64-col tiles)

  const int ar  = tid >> 1;            // A staging row 0..127
  const int ach = (tid & 1) << 4;      // 0 or 16 floats
  const int br  = tid >> 2;            // B staging row 0..63
  const int bch = (tid & 3) << 3;      // 0,8,16,24 floats

  const int gr = blkm * 128 + ar;      // global A row = b*512+s
  const int bb = blkm >> 2;            // batch (tile never crosses batch)
  const int gh = blkn * 64 + br;       // global W1 row = h

  const int rl = lane & 15;
  const int kq = (lane >> 4) << 3;     // k-offset (shorts) for MFMA frag

  f32x4 acc[4][2];
  #pragma unroll
  for (int i = 0; i < 4; ++i)
    #pragma unroll
    for (int j = 0; j < 2; ++j)
      acc[i][j] = (f32x4){0.f, 0.f, 0.f, 0.f};

  float raA[16], rbA[8], raB[16], rbB[8];

#define LOADS(RA, RB, KTG) do {                                             \
    const int kt_ = (KTG);                                                  \
    const int offA_ = ((kt_ & 15) << 5) | ach;                              \
    const int reg_ = kt_ >> 4;                                              \
    const float* pa_;                                                       \
    if      (reg_ == 0) pa_ = face + (size_t)gr * 512 + offA_;              \
    else if (reg_ == 1) pa_ = fcf  + (size_t)gr * 512 + offA_;              \
    else if (reg_ == 2) pa_ = imgf + (size_t)gr * 512 + offA_;              \
    else                pa_ = labf + (size_t)bb * 512 + offA_;              \
    _Pragma("unroll")                                                       \
    for (int i_ = 0; i_ < 4; ++i_) {                                        \
      f32x4 va_ = *(const f32x4*)(pa_ + 4 * i_);                            \
      RA[4*i_+0] = va_[0]; RA[4*i_+1] = va_[1];                             \
      RA[4*i_+2] = va_[2]; RA[4*i_+3] = va_[3];                             \
    }                                                                       \
    const float* pw_ = W1 + (size_t)gh * WSTRIDE + (kt_ << 5) + bch;        \
    _Pragma("unroll")                                                       \
    for (int i_ = 0; i_ < 2; ++i_) {                                        \
      f32x4 vb_ = *(const f32x4*)(pw_ + 4 * i_);                            \
      RB[4*i_+0] = vb_[0]; RB[4*i_+1] = vb_[1];                             \
      RB[4*i_+2] = vb_[2]; RB[4*i_+3] = vb_[3];                             \
    }                                                                       \
  } while (0)

#define WLDS(RA, RB, BUF) do {                                              \
    ushort8 a0_, a1_, b0_;                                                  \
    _Pragma("unroll")                                                       \
    for (int j_ = 0; j_ < 8; ++j_) {                                        \
      a0_[j_] = f2b(RA[j_]);   a1_[j_] = f2b(RA[8 + j_]);                   \
      b0_[j_] = f2b(RB[j_]);                                                \
    }                                                                       \
    *(ushort8*)&As[BUF][ar * LDSK + ach]     = a0_;                         \
    *(ushort8*)&As[BUF][ar * LDSK + ach + 8] = a1_;                         \
    *(ushort8*)&Bs[BUF][br * LDSK + bch]     = b0_;                         \
  } while (0)

#define COMPUTE(BUF) do {                                                   \
    bf16x8 af_[4], bf_[2];                                                  \
    _Pragma("unroll")                                                       \
    for (int m_ = 0; m_ < 4; ++m_)                                          \
      af_[m_] = *(const bf16x8*)&As[BUF][(wr*64 + m_*16 + rl) * LDSK + kq]; \
    _Pragma("unroll")                                                       \
    for (int n_ = 0; n_ < 2; ++n_)                                          \
      bf_[n_] = *(const bf16x8*)&Bs[BUF][(wc*32 + n_*16 + rl) * LDSK + kq]; \
    _Pragma("unroll")                                                       \
    for (int m_ = 0; m_ < 4; ++m_)                                          \
      _Pragma("unroll")                                                     \
      for (int n_ = 0; n_ < 2; ++n_)                                        \
        acc[m_][n_] = __builtin_amdgcn_mfma_f32_16x16x32_bf16(              \
            af_[m_], bf_[n_], acc[m_][n_], 0, 0, 0);                        \
  } while (0)

  // Prologue: tiles 0 and 1 in flight; tile 0 -> LDS buf0.
  LOADS(raA, rbA, 0);
  LOADS(raB, rbB, 1);
  WLDS(raA, rbA, 0);
  __syncthreads();

  // 64 K-steps, processed 2 per outer iteration (static set/buf phasing).
  #pragma unroll 1
  for (int kt = 0; kt < 64; kt += 2) {
    // even phase: consume buf0 (tile kt)
    if (kt + 2 < 64) LOADS(raA, rbA, kt + 2);  // set A free: tile kt already in LDS
    COMPUTE(0);
    WLDS(raB, rbB, 1);                         // tile kt+1 (loaded last iter -> landed)
    __syncthreads();
    // odd phase: consume buf1 (tile kt+1)
    if (kt + 3 < 64) LOADS(raB, rbB, kt + 3);
    COMPUTE(1);
    if (kt + 2 < 64) WLDS(raA, rbA, 0);        // tile kt+2
    __syncthreads();
  }

  // C/D layout: col=lane&15, row=(lane>>4)*4+reg (m89-verified)
  const int crow = blkm * 128 + wr * 64;
  const int ccol = blkn * 64 + wc * 32 + rl;
  #pragma unroll
  for (int m = 0; m < 4; ++m)
    #pragma unroll
    for (int n = 0; n < 2; ++n)
      #pragma unroll
      for (int j = 0; j < 4; ++j) {
        const int row = crow + m * 16 + (lane >> 4) * 4 + j;
        pb[(size_t)row * 512 + ccol + n * 16] = acc[m][n][j];
      }

#undef LOADS
#undef WLDS
#undef COMPUTE
}

// ---------------------------------------------------------------------------
// Kernel 2: part_mem[b][m][h] = sum_d memory[b,m,d]*W1[h,2048+d] + b1[h]
// fp32 exact. Grid (32 b, 8 h-tiles) = 256 blocks. Lanes-over-d coalesced
// W reads + butterfly reduce. W1b is 512 wide: chunks at l*4 and 256+l*4.
// ---------------------------------------------------------------------------
__global__ __launch_bounds__(256)
void pm_kernel(const float* __restrict__ memory,
               const float* __restrict__ W1,
               const float* __restrict__ b1,
               float* __restrict__ pm)
{
  __shared__ float ms[NM * 512];
  const int b  = blockIdx.x;
  const int ht = blockIdx.y;
  const int t  = threadIdx.x;
  const int w  = t >> 6;
  const int l  = t & 63;

  const float* src = memory + (size_t)b * NM * 512;
  #pragma unroll
  for (int i = 0; i < 4; ++i)
    ((f32x4*)ms)[t + i * 256] = ((const f32x4*)src)[t + i * 256];
  __syncthreads();

  #pragma unroll 1
  for (int i = 0; i < 16; ++i) {
    const int h = ht * 64 + w * 16 + i;
    const float* wrow = W1 + (size_t)h * WSTRIDE + 2048;
    const f32x4 w0 = *(const f32x4*)(wrow + l * 4);        // d: 0..255
    const f32x4 w1 = *(const f32x4*)(wrow + 256 + l * 4);  // d: 256..511
    float part[NM];
    #pragma unroll
    for (int m = 0; m < NM; ++m) {
      const f32x4 m0 = *(const f32x4*)&ms[m * 512 + l * 4];
      const f32x4 m1 = *(const f32x4*)&ms[m * 512 + 256 + l * 4];
      part[m] = w0[0]*m0[0] + w0[1]*m0[1] + w0[2]*m0[2] + w0[3]*m0[3]
              + w1[0]*m1[0] + w1[1]*m1[1] + w1[2]*m1[2] + w1[3]*m1[3];
    }
    #pragma unroll
    for (int off = 32; off >= 1; off >>= 1)
      #pragma unroll
      for (int m = 0; m < NM; ++m)
        part[m] += __shfl_xor(part[m], off);
    if (l == 0) {
      const float bias = b1[h];
      #pragma unroll
      for (int m = 0; m < NM; ++m)
        pm[((size_t)b * NM + m) * 512 + h] = part[m] + bias;
    }
  }
}

// ---------------------------------------------------------------------------
// Kernel 3: e[b][m*512+s] = sum_h tanh(pb[b,s,h]+pm[b,m,h]) * w2[h]
// Re-tiled for occupancy: grid (32, 64) = 2048 blocks, 256 threads,
// thread = (s in 8, m in 8, h-quarter in 4), 2-stage shfl reduce over h.
// LDS bank-skew: row stride 580 (=4 mod 32), quarter stride 144 (=16 mod 32)
// -> max 2-way (free). ~39 KB -> 4 blocks/CU, 16 waves.
// FIX vs R4 draft: pm staging is 1024 f32x4 (4/thread), not 256.
// ---------------------------------------------------------------------------
#define ERST 580   // row stride (f32): 4*144 + 4
#define EQST 144   // h-quarter stride (f32)

__global__ __launch_bounds__(256)
void e_kernel(const float* __restrict__ pb,
              const float* __restrict__ pm,
              const float* __restrict__ w2,
              float* __restrict__ e)
{
  __shared__ float pbs[8 * ERST];
  __shared__ float pms[8 * ERST];
  __shared__ float w2s[4 * 136];

  const int b  = blockIdx.x;   // 0..31
  const int st = blockIdx.y;   // 0..63
  const int t  = threadIdx.x;  // 0..255
  const int s0 = st * 8;

  // stage pb rows [s0, s0+8): 1024 f32x4, 4 per thread, skewed layout
  const f32x4* psrc = (const f32x4*)(pb + ((size_t)b * NS + s0) * 512);
  #pragma unroll
  for (int i = 0; i < 4; ++i) {
    const int fi = t + i * 256;
    const f32x4 v = psrc[fi];
    const int f32i = fi * 4;
    const int row = f32i >> 9, col = f32i & 511;
    *(f32x4*)&pbs[row * ERST + (col >> 7) * EQST + (col & 127)] = v;
  }
  // stage pm (8 m-rows x 512 = 1024 f32x4): 4 per thread (FIXED)
  {
    const f32x4* msrc = (const f32x4*)(pm + (size_t)b * NM * 512);
    #pragma unroll
    for (int i = 0; i < 4; ++i) {
      const int fi = t + i * 256;
      const f32x4 v = msrc[fi];
      const int f32i = fi * 4;
      const int row = f32i >> 9, col = f32i & 511;
      *(f32x4*)&pms[row * ERST + (col >> 7) * EQST + (col & 127)] = v;
    }
  }
  if (t < 128) {
    const f32x4 v = ((const f32x4*)w2)[t];
    const int f32i = t * 4;
    *(f32x4*)&w2s[(f32i >> 7) * 136 + (f32i & 127)] = v;
  }
  __syncthreads();

  const int q  = t & 3;          // h-quarter
  const int m  = (t >> 2) & 7;
  const int sl = t >> 5;
  const float* prow = &pbs[sl * ERST + q * EQST];
  const float* mrow = &pms[m * ERST + q * EQST];
  const float* wq   = &w2s[q * 136];

  float acc = 0.f;
  #pragma unroll 4
  for (int hh = 0; hh < 128; hh += 4) {
    const f32x4 pv = *(const f32x4*)&prow[hh];
    const f32x4 mv = *(const f32x4*)&mrow[hh];
    const f32x4 wv = *(const f32x4*)&wq[hh];
    #pragma unroll
    for (int j = 0; j < 4; ++j) {
      const float x  = pv[j] + mv[j];
      const float ex = __expf(x + x);                   // exp(2x)
      acc += wv[j] * (1.f - __fdividef(2.f, ex + 1.f)); // w2 * tanh(x)
    }
  }
  acc += __shfl_xor(acc, 1);
  acc += __shfl_xor(acc, 2);
  if (q == 0)
    e[(size_t)b * (NM * NS) + m * NS + s0 + sl] = acc;
}

// ---------------------------------------------------------------------------
// Kernel 4: per-batch softmax over 4096, mask (j mod 512), renorm.
// Writes alpha and ws[s] = sum_m alpha[m][s] (for ctx kernel).
// ---------------------------------------------------------------------------
__global__ __launch_bounds__(256)
void softmax_kernel(const float* __restrict__ e,
                    const float* __restrict__ face_mask,
                    float* __restrict__ out_alpha,
                    float* __restrict__ wsum)
{
  __shared__ float ev[NM * NS];
  __shared__ float msk[NS];
  __shared__ float redX[4], redA[4], redM[4];

  const int b = blockIdx.x;
  const int t = threadIdx.x;
  const int lane = t & 63;
  const int wv = t >> 6;

  const float* erow = e + (size_t)b * (NM * NS);
  #pragma unroll
  for (int i = 0; i < 4; ++i)
    ((f32x4*)ev)[t + i * 256] = ((const f32x4*)erow)[t + i * 256];
  if (t < 128)
    ((f32x4*)msk)[t] = ((const f32x4*)(face_mask + (size_t)b * NS))[t];
  __syncthreads();

  float mx = -3.402823466e38f;
  for (int i = t; i < NM * NS; i += 256) mx = fmaxf(mx, ev[i]);
  #pragma unroll
  for (int o = 32; o >= 1; o >>= 1) mx = fmaxf(mx, __shfl_xor(mx, o));
  if (lane == 0) redX[wv] = mx;
  __syncthreads();
  mx = fmaxf(fmaxf(redX[0], redX[1]), fmaxf(redX[2], redX[3]));

  float sA = 0.f, sM = 0.f;
  for (int i = t; i < NM * NS; i += 256) {
    const float p = __expf(ev[i] - mx);
    ev[i] = p;
    sA += p;
    sM += p * msk[i & 511];
  }
  #pragma unroll
  for (int o = 32; o >= 1; o >>= 1) {
    sA += __shfl_xor(sA, o);
    sM += __shfl_xor(sM, o);
  }
  if (lane == 0) { redA[wv] = sA; redM[wv] = sM; }
  __syncthreads();
  sA = redA[0] + redA[1] + redA[2] + redA[3];
  sM = redM[0] + redM[1] + redM[2] + redM[3];

  const float rr = sM / sA;
  const float scale = 1.f / (sA * (rr + FEPS));

  for (int i = t; i < NM * NS; i += 256) {
    const float a = ev[i] * msk[i & 511] * scale;
    ev[i] = a;
    out_alpha[(size_t)b * (NM * NS) + i] = a;
  }
  __syncthreads();

  for (int s = t; s < NS; s += 256) {
    float w = 0.f;
    #pragma unroll
    for (int m = 0; m < NM; ++m) w += ev[m * NS + s];
    wsum[(size_t)b * NS + s] = w;
  }
}

// ---------------------------------------------------------------------------
// Kernel 5: context[b][d] = sum_s ws[s] * face[b,s,d]
// Grid (32, 8 s-chunks) = 256 blocks; f32x4 coalesced; atomicAdd partials.
// ---------------------------------------------------------------------------
__global__ __launch_bounds__(128)
void ctx_kernel(const float* __restrict__ wsum,
                const float* __restrict__ face,
                float* __restrict__ out_ctx)
{
  const int b  = blockIdx.x;
  const int sq = blockIdx.y;
  const int t  = threadIdx.x;   // 0..127 -> f32x4 over d

  f32x4 acc = (f32x4){0.f, 0.f, 0.f, 0.f};
  const int s0 = sq * 64;
  #pragma unroll 4
  for (int si = 0; si < 64; ++si) {
    const int s = s0 + si;
    const float w = wsum[(size_t)b * NS + s];
    const f32x4 fv = ((const f32x4*)(face + ((size_t)b * NS + s) * 512))[t];
    acc[0] += w * fv[0]; acc[1] += w * fv[1];
    acc[2] += w * fv[2]; acc[3] += w * fv[3];
  }
  float* dst = out_ctx + (size_t)b * 512 + t * 4;
  atomicAdd(dst + 0, acc[0]);
  atomicAdd(dst + 1, acc[1]);
  atomicAdd(dst + 2, acc[2]);
  atomicAdd(dst + 3, acc[3]);
}

// ---------------------------------------------------------------------------
extern "C" void kernel_launch(void* const* d_in, const int* in_sizes, int n_in,
                              void* d_out, int out_size, void* d_ws, size_t ws_size,
                              hipStream_t stream)
{
  const float* fc_feat  = (const float*)d_in[0];
  const float* img_feat = (const float*)d_in[1];
  const float* label    = (const float*)d_in[2];
  const float* memory   = (const float*)d_in[3];
  const float* face     = (const float*)d_in[4];
  const float* fmask    = (const float*)d_in[5];
  const float* W1       = (const float*)d_in[6];
  const float* b1       = (const float*)d_in[7];
  const float* w2       = (const float*)d_in[8];

  float* out       = (float*)d_out;
  float* alpha_out = out;                        // [32, 4096]
  float* ctx_out   = out + (size_t)NB * NM * NS; // [32, 512]

  const size_t szPB = (size_t)NB * NS * 512 * 4;   // 33.5 MB
  const size_t szPM = (size_t)NB * NM * 512 * 4;
  const size_t szE  = (size_t)NB * NM * NS * 4;

  char* ws = (char*)d_ws;
  float* pb   = (float*)ws;
  float* pm   = (float*)(ws + szPB);
  float* ee   = (float*)(ws + szPB + szPM);
  float* wsum = (float*)(ws + szPB + szPM + szE);

  hipMemsetAsync(ctx_out, 0, (size_t)NB * 512 * 4, stream);

  // concat order in reference: [face, fc, img, label]
  gemm_base_kernel<<<1024, 256, 0, stream>>>(face, fc_feat, img_feat, label, W1, pb);
  pm_kernel<<<dim3(NB, 8), 256, 0, stream>>>(memory, W1, b1, pm);
  e_kernel<<<dim3(NB, NS / 8), 256, 0, stream>>>(pb, pm, w2, ee);
  softmax_kernel<<<NB, 256, 0, stream>>>(ee, fmask, alpha_out, wsum);
  ctx_kernel<<<dim3(NB, 8), 128, 0, stream>>>(wsum, face, ctx_out);
}

// Round 10
// 287.036 us; speedup vs baseline: 1.2303x; 1.0346x over previous
//
#include <hip/hip_runtime.h>
#include <hip/hip_bf16.h>
#include <math.h>

// Problem dims
#define NB 32
#define NS 512
#define NM 8
#define NH 512
#define WSTRIDE 2560   // W1 row stride (DIM1+DIM2)
#define FEPS 1e-5f

typedef __attribute__((ext_vector_type(4))) float f32x4;
typedef __attribute__((ext_vector_type(8))) short bf16x8;

__device__ __forceinline__ unsigned short f2b(float f) {
  union { __hip_bfloat16 h; unsigned short u; } cv;
  cv.h = __float2bfloat16(f);
  return cv.u;
}

// global_load_lds: 16B per lane, dest = wave-uniform LDS base + lane*16.
__device__ __forceinline__ void gll16(const float* g, float* l) {
  __builtin_amdgcn_global_load_lds(
      (const __attribute__((address_space(1))) void*)g,
      (__attribute__((address_space(3))) void*)l, 16, 0, 0);
}

// ---------------------------------------------------------------------------
// Kernel 1: part_base[b*S+s][h] = sum_d base[b,s,d] * W1[h,d]   (bf16 MFMA)
// m97 structure: global_load_lds staging (NO VGPR landing -> nothing for the
// compiler to spill or sink: R6's reg-prefetch was defeated that way,
// VGPR_Count=64 < 80 live needed).
// Stages FP32 tiles; fp32->bf16 conversion happens at LDS->fragment read
// (VALU was 9% idle). Tile 128x128, BK=32, 4 waves (2x2), wave tile 64x64,
// acc[4][4]. LDS 64 KB -> 2 blocks/CU (grid 512 caps at 2 anyway).
// Source-preswizzle (rule #21 both-sides): LDS row of 8x16B units holds
// original unit (u ^ (row&7)); gload source address carries the inverse.
// ---------------------------------------------------------------------------
__global__ __launch_bounds__(256)
void gemm_base_kernel(const float* __restrict__ face,
                      const float* __restrict__ fcf,
                      const float* __restrict__ imgf,
                      const float* __restrict__ labf,
                      const float* __restrict__ W1,
                      float* __restrict__ pb)
{
  __shared__ __align__(16) float Af[2][128 * 32];   // 16 KB per buf
  __shared__ __align__(16) float Bf[2][128 * 32];

  const int tid  = threadIdx.x;
  const int lane = tid & 63;
  const int wid  = tid >> 6;
  const int wr   = wid >> 1;           // wave row (0..1)
  const int wc   = wid & 1;            // wave col (0..1)

  // XCD swizzle (bijective: 512 % 8 == 0)
  const int bid = blockIdx.x;
  const int cpx = gridDim.x >> 3;      // 64
  const int sid = (bid & 7) * cpx + (bid >> 3);
  const int blkm = sid >> 2;           // 0..127 (128-row tiles)
  const int blkn = sid & 3;            // 0..3   (128-col tiles)
  const int bb   = blkm >> 2;          // batch (tile never crosses batch)

  const int rl = lane & 15;
  const int g2 = (lane >> 4) << 1;     // original 16B-unit pair base for frag

// Stage K-tile KT into buffer BUF. Per thread: 4 A-chunks + 4 B-chunks of 16B.
// chunk c: row = c>>3 (128B fp32 rows), unit = c&7; source unit = unit^(row&7).
#define STAGE(BUF, KT) do {                                                  \
    const int kt_ = (KT);                                                    \
    const int seg_ = kt_ >> 4;                                               \
    const int colf_ = (kt_ & 15) << 5;   /* segment-local float col */       \
    _Pragma("unroll")                                                        \
    for (int i_ = 0; i_ < 4; ++i_) {                                         \
      const int c_   = tid + (i_ << 8);                                      \
      const int row_ = c_ >> 3;                                              \
      const int sw_  = ((c_ ^ row_) & 7) << 2;   /* (unit^(row&7))*4 */      \
      const float* ga_;                                                      \
      if (seg_ == 3)                                                         \
        ga_ = labf + (size_t)bb * 512 + colf_ + sw_;                         \
      else {                                                                 \
        const float* ab_ = (seg_ == 0) ? face : (seg_ == 1) ? fcf : imgf;    \
        ga_ = ab_ + (size_t)(blkm * 128 + row_) * 512 + colf_ + sw_;         \
      }                                                                      \
      const float* gb_ = W1 + (size_t)(blkn * 128 + row_) * WSTRIDE          \
                            + (kt_ << 5) + sw_;                              \
      const int cb_ = (c_ & ~63) << 2;   /* wave-uniform float base */       \
      gll16(ga_, &Af[BUF][cb_]);                                             \
      gll16(gb_, &Bf[BUF][cb_]);                                             \
    }                                                                        \
  } while (0)

// Read fragment (8 fp32 -> 8 bf16) for row ROW from LDS buffer LP.
#define FRAG(DST, LP, ROW) do {                                              \
    const int row_ = (ROW);                                                  \
    const int ua_  = g2 ^ (row_ & 7);                                        \
    const f32x4 h0_ = *(const f32x4*)&LP[row_ * 32 + ua_ * 4];               \
    const f32x4 h1_ = *(const f32x4*)&LP[row_ * 32 + (ua_ ^ 1) * 4];         \
    DST[0] = (short)f2b(h0_[0]); DST[1] = (short)f2b(h0_[1]);                \
    DST[2] = (short)f2b(h0_[2]); DST[3] = (short)f2b(h0_[3]);                \
    DST[4] = (short)f2b(h1_[0]); DST[5] = (short)f2b(h1_[1]);                \
    DST[6] = (short)f2b(h1_[2]); DST[7] = (short)f2b(h1_[3]);                \
  } while (0)

#define COMPUTE(BUF) do {                                                    \
    bf16x8 af_[4], bf_[4];                                                   \
    _Pragma("unroll")                                                        \
    for (int m_ = 0; m_ < 4; ++m_) FRAG(af_[m_], Af[BUF], wr*64 + m_*16 + rl);\
    _Pragma("unroll")                                                        \
    for (int n_ = 0; n_ < 4; ++n_) FRAG(bf_[n_], Bf[BUF], wc*64 + n_*16 + rl);\
    _Pragma("unroll")                                                        \
    for (int m_ = 0; m_ < 4; ++m_)                                           \
      _Pragma("unroll")                                                      \
      for (int n_ = 0; n_ < 4; ++n_)                                         \
        acc[m_][n_] = __builtin_amdgcn_mfma_f32_16x16x32_bf16(               \
            af_[m_], bf_[n_], acc[m_][n_], 0, 0, 0);                         \
  } while (0)

  f32x4 acc[4][4];
  #pragma unroll
  for (int i = 0; i < 4; ++i)
    #pragma unroll
    for (int j = 0; j < 4; ++j)
      acc[i][j] = (f32x4){0.f, 0.f, 0.f, 0.f};

  STAGE(0, 0);
  __syncthreads();                     // vmcnt(0) drain -> buf0 ready

  int buf = 0;
  #pragma unroll 1
  for (int kt = 0; kt < 64; ++kt) {
    if (kt < 63) STAGE(buf ^ 1, kt + 1);   // async into other buffer
    COMPUTE(buf);
    __syncthreads();                       // drains staged loads + readers
    buf ^= 1;
  }

  // C/D layout: col=lane&15, row=(lane>>4)*4+reg (m89-verified; R1-validated)
  const int crow = blkm * 128 + wr * 64;
  const int ccol = blkn * 128 + wc * 64 + rl;
  #pragma unroll
  for (int m = 0; m < 4; ++m)
    #pragma unroll
    for (int n = 0; n < 4; ++n)
      #pragma unroll
      for (int j = 0; j < 4; ++j) {
        const int row = crow + m * 16 + (lane >> 4) * 4 + j;
        pb[(size_t)row * 512 + ccol + n * 16] = acc[m][n][j];
      }

#undef STAGE
#undef FRAG
#undef COMPUTE
}

// ---------------------------------------------------------------------------
// Kernel 2: part_mem[b][m][h] = sum_d memory[b,m,d]*W1[h,2048+d] + b1[h]
// fp32 exact. Validated in R6 — unchanged.
// ---------------------------------------------------------------------------
__global__ __launch_bounds__(256)
void pm_kernel(const float* __restrict__ memory,
               const float* __restrict__ W1,
               const float* __restrict__ b1,
               float* __restrict__ pm)
{
  __shared__ float ms[NM * 512];
  const int b  = blockIdx.x;
  const int ht = blockIdx.y;
  const int t  = threadIdx.x;
  const int w  = t >> 6;
  const int l  = t & 63;

  const float* src = memory + (size_t)b * NM * 512;
  #pragma unroll
  for (int i = 0; i < 4; ++i)
    ((f32x4*)ms)[t + i * 256] = ((const f32x4*)src)[t + i * 256];
  __syncthreads();

  #pragma unroll 1
  for (int i = 0; i < 16; ++i) {
    const int h = ht * 64 + w * 16 + i;
    const float* wrow = W1 + (size_t)h * WSTRIDE + 2048;
    const f32x4 w0 = *(const f32x4*)(wrow + l * 4);        // d: 0..255
    const f32x4 w1 = *(const f32x4*)(wrow + 256 + l * 4);  // d: 256..511
    float part[NM];
    #pragma unroll
    for (int m = 0; m < NM; ++m) {
      const f32x4 m0 = *(const f32x4*)&ms[m * 512 + l * 4];
      const f32x4 m1 = *(const f32x4*)&ms[m * 512 + 256 + l * 4];
      part[m] = w0[0]*m0[0] + w0[1]*m0[1] + w0[2]*m0[2] + w0[3]*m0[3]
              + w1[0]*m1[0] + w1[1]*m1[1] + w1[2]*m1[2] + w1[3]*m1[3];
    }
    #pragma unroll
    for (int off = 32; off >= 1; off >>= 1)
      #pragma unroll
      for (int m = 0; m < NM; ++m)
        part[m] += __shfl_xor(part[m], off);
    if (l == 0) {
      const float bias = b1[h];
      #pragma unroll
      for (int m = 0; m < NM; ++m)
        pm[((size_t)b * NM + m) * 512 + h] = part[m] + bias;
    }
  }
}

// ---------------------------------------------------------------------------
// Kernel 3: e[b][m*512+s] = sum_h tanh(pb[b,s,h]+pm[b,m,h]) * w2[h]
// Lean rewrite: pb read directly from global (L3-resident; 8 lanes with the
// same m-group broadcast one 16B request). Only pm (16KB, skewed) + w2 in
// LDS. Thread = (m, s_local); full 512-h loop, no reduce. ~6 VALU + 2 trans
// per element.
// ---------------------------------------------------------------------------
__global__ __launch_bounds__(256)
void e_kernel(const float* __restrict__ pb,
              const float* __restrict__ pm,
              const float* __restrict__ w2,
              float* __restrict__ e)
{
  __shared__ float pms[NM * 520];   // row stride 520 (mod 32 = 8): m-rows spread
  __shared__ float w2s[512];

  const int b  = blockIdx.x;   // 0..31
  const int st = blockIdx.y;   // 0..15
  const int t  = threadIdx.x;  // 0..255

  // stage pm: 8 rows x 512 f32 = 1024 f32x4, 4/thread
  {
    const f32x4* msrc = (const f32x4*)(pm + (size_t)b * NM * 512);
    #pragma unroll
    for (int i = 0; i < 4; ++i) {
      const int fi = t + i * 256;
      const int row = fi >> 7, col = (fi & 127) << 2;
      *(f32x4*)&pms[row * 520 + col] = msrc[fi];
    }
  }
  if (t < 128)
    ((f32x4*)w2s)[t] = ((const f32x4*)w2)[t];
  __syncthreads();

  const int m  = t & 7;
  const int sl = t >> 3;              // 0..31
  const int s  = st * 32 + sl;

  const float* prow = pb + ((size_t)b * NS + s) * 512;
  const float* mrow = &pms[m * 520];

  float acc = 0.f;
  #pragma unroll 4
  for (int h = 0; h < 512; h += 4) {
    const f32x4 pv = *(const f32x4*)&prow[h];
    const f32x4 mv = *(const f32x4*)&mrow[h];
    const f32x4 wv = *(const f32x4*)&w2s[h];
    #pragma unroll
    for (int j = 0; j < 4; ++j) {
      const float x  = pv[j] + mv[j];
      const float ex = __expf(x + x);                   // exp(2x)
      acc += wv[j] * (1.f - __fdividef(2.f, ex + 1.f)); // w2 * tanh(x)
    }
  }
  e[(size_t)b * (NM * NS) + m * NS + s] = acc;
}

// ---------------------------------------------------------------------------
// Kernel 4: per-batch softmax over 4096, mask (j mod 512), renorm.
// Validated — unchanged.
// ---------------------------------------------------------------------------
__global__ __launch_bounds__(256)
void softmax_kernel(const float* __restrict__ e,
                    const float* __restrict__ face_mask,
                    float* __restrict__ out_alpha,
                    float* __restrict__ wsum)
{
  __shared__ float ev[NM * NS];
  __shared__ float msk[NS];
  __shared__ float redX[4], redA[4], redM[4];

  const int b = blockIdx.x;
  const int t = threadIdx.x;
  const int lane = t & 63;
  const int wv = t >> 6;

  const float* erow = e + (size_t)b * (NM * NS);
  #pragma unroll
  for (int i = 0; i < 4; ++i)
    ((f32x4*)ev)[t + i * 256] = ((const f32x4*)erow)[t + i * 256];
  if (t < 128)
    ((f32x4*)msk)[t] = ((const f32x4*)(face_mask + (size_t)b * NS))[t];
  __syncthreads();

  float mx = -3.402823466e38f;
  for (int i = t; i < NM * NS; i += 256) mx = fmaxf(mx, ev[i]);
  #pragma unroll
  for (int o = 32; o >= 1; o >>= 1) mx = fmaxf(mx, __shfl_xor(mx, o));
  if (lane == 0) redX[wv] = mx;
  __syncthreads();
  mx = fmaxf(fmaxf(redX[0], redX[1]), fmaxf(redX[2], redX[3]));

  float sA = 0.f, sM = 0.f;
  for (int i = t; i < NM * NS; i += 256) {
    const float p = __expf(ev[i] - mx);
    ev[i] = p;
    sA += p;
    sM += p * msk[i & 511];
  }
  #pragma unroll
  for (int o = 32; o >= 1; o >>= 1) {
    sA += __shfl_xor(sA, o);
    sM += __shfl_xor(sM, o);
  }
  if (lane == 0) { redA[wv] = sA; redM[wv] = sM; }
  __syncthreads();
  sA = redA[0] + redA[1] + redA[2] + redA[3];
  sM = redM[0] + redM[1] + redM[2] + redM[3];

  const float rr = sM / sA;
  const float scale = 1.f / (sA * (rr + FEPS));

  for (int i = t; i < NM * NS; i += 256) {
    const float a = ev[i] * msk[i & 511] * scale;
    ev[i] = a;
    out_alpha[(size_t)b * (NM * NS) + i] = a;
  }
  __syncthreads();

  for (int s = t; s < NS; s += 256) {
    float w = 0.f;
    #pragma unroll
    for (int m = 0; m < NM; ++m) w += ev[m * NS + s];
    wsum[(size_t)b * NS + s] = w;
  }
}

// ---------------------------------------------------------------------------
// Kernel 5: context[b][d] = sum_s ws[s] * face[b,s,d]
// Validated — unchanged.
// ---------------------------------------------------------------------------
__global__ __launch_bounds__(128)
void ctx_kernel(const float* __restrict__ wsum,
                const float* __restrict__ face,
                float* __restrict__ out_ctx)
{
  const int b  = blockIdx.x;
  const int sq = blockIdx.y;
  const int t  = threadIdx.x;   // 0..127 -> f32x4 over d

  f32x4 acc = (f32x4){0.f, 0.f, 0.f, 0.f};
  const int s0 = sq * 64;
  #pragma unroll 4
  for (int si = 0; si < 64; ++si) {
    const int s = s0 + si;
    const float w = wsum[(size_t)b * NS + s];
    const f32x4 fv = ((const f32x4*)(face + ((size_t)b * NS + s) * 512))[t];
    acc[0] += w * fv[0]; acc[1] += w * fv[1];
    acc[2] += w * fv[2]; acc[3] += w * fv[3];
  }
  float* dst = out_ctx + (size_t)b * 512 + t * 4;
  atomicAdd(dst + 0, acc[0]);
  atomicAdd(dst + 1, acc[1]);
  atomicAdd(dst + 2, acc[2]);
  atomicAdd(dst + 3, acc[3]);
}

// ---------------------------------------------------------------------------
extern "C" void kernel_launch(void* const* d_in, const int* in_sizes, int n_in,
                              void* d_out, int out_size, void* d_ws, size_t ws_size,
                              hipStream_t stream)
{
  const float* fc_feat  = (const float*)d_in[0];
  const float* img_feat = (const float*)d_in[1];
  const float* label    = (const float*)d_in[2];
  const float* memory   = (const float*)d_in[3];
  const float* face     = (const float*)d_in[4];
  const float* fmask    = (const float*)d_in[5];
  const float* W1       = (const float*)d_in[6];
  const float* b1       = (const float*)d_in[7];
  const float* w2       = (const float*)d_in[8];

  float* out       = (float*)d_out;
  float* alpha_out = out;                        // [32, 4096]
  float* ctx_out   = out + (size_t)NB * NM * NS; // [32, 512]

  const size_t szPB = (size_t)NB * NS * 512 * 4;   // 33.5 MB
  const size_t szPM = (size_t)NB * NM * 512 * 4;
  const size_t szE  = (size_t)NB * NM * NS * 4;

  char* ws = (char*)d_ws;
  float* pb   = (float*)ws;
  float* pm   = (float*)(ws + szPB);
  float* ee   = (float*)(ws + szPB + szPM);
  float* wsum = (float*)(ws + szPB + szPM + szE);

  hipMemsetAsync(ctx_out, 0, (size_t)NB * 512 * 4, stream);

  // concat order in reference: [face, fc, img, label]
  gemm_base_kernel<<<512, 256, 0, stream>>>(face, fc_feat, img_feat, label, W1, pb);
  pm_kernel<<<dim3(NB, 8), 256, 0, stream>>>(memory, W1, b1, pm);
  e_kernel<<<dim3(NB, 16), 256, 0, stream>>>(pb, pm, w2, ee);
  softmax_kernel<<<NB, 256, 0, stream>>>(ee, fmask, alpha_out, wsum);
  ctx_kernel<<<dim3(NB, 8), 128, 0, stream>>>(wsum, face, ctx_out);
}